// Round 1
// baseline (7354.301 us; speedup 1.0000x reference)
//
#include <hip/hip_runtime.h>

#define N_NODES 100000
#define N_EDGES 2000000
#define EPS 1e-9f
#define NORMC 0.22360679774997896f  // 1/sqrt(20)

__device__ __forceinline__ float silu_f(float x) {
    return x / (1.0f + __expf(-x));
}

// ---------------------------------------------------------------------------
// Workspace layout (floats):
//   xn_norm : 3,200,000
//   acc1    : 3,200,000
//   acc2    : 3,200,000
//   BpA     : 34,848   (n2e extended bilinear  [33*33][32], k contiguous)
//   BpB     : 34,848   (e2n extended bilinear  [33*33][32])
//   BpN     : 4,224    (node extended bilinear [33*4][32])
//   WxE     : 1,056    (mix_xe linear part   [33][32])
//   CtE     : 1,056    (mix_xe attr part     [33][32])
// ---------------------------------------------------------------------------

__global__ void prep_kernel(const float* __restrict__ W_n2e, const float* __restrict__ B_n2e,
                            const float* __restrict__ b_n2e,
                            const float* __restrict__ W_e2n, const float* __restrict__ B_e2n,
                            const float* __restrict__ b_e2n,
                            const float* __restrict__ W_mix_xn, const float* __restrict__ B_mix_xn,
                            const float* __restrict__ b_mix_xn,
                            const float* __restrict__ W_mix_xe, const float* __restrict__ B_mix_xe,
                            const float* __restrict__ b_mix_xe,
                            float* __restrict__ BpA, float* __restrict__ BpB,
                            float* __restrict__ BpN, float* __restrict__ WxE,
                            float* __restrict__ CtE) {
    int t = blockIdx.x * blockDim.x + threadIdx.x;
    if (t < 34848) {
        // n2e: M[k,i,j], i,j in [0,33)
        int k = t & 31, ij = t >> 5;
        int i = ij / 33, j = ij - i * 33;
        float r;
        if (i < 32 && j < 32) {
            r = 0.f;
            #pragma unroll
            for (int m = 0; m < 32; ++m) r += W_n2e[k*96 + 64 + m] * B_n2e[m*1024 + i*32 + j];
        } else if (i < 32) {        // j == 32 : Wa part
            r = W_n2e[k*96 + i];
        } else if (j < 32) {        // i == 32 : Wb part
            r = W_n2e[k*96 + 32 + j];
        } else {                    // bias
            r = b_n2e[k];
        }
        BpA[ij*32 + k] = r;
    } else if (t < 69696) {
        int u = t - 34848;
        int k = u & 31, ij = u >> 5;
        int i = ij / 33, j = ij - i * 33;
        float r;
        if (i < 32 && j < 32) {
            r = 0.f;
            #pragma unroll
            for (int m = 0; m < 32; ++m) r += W_e2n[k*96 + 64 + m] * B_e2n[m*1024 + i*32 + j];
        } else if (i < 32) {
            r = W_e2n[k*96 + i];
        } else if (j < 32) {
            r = W_e2n[k*96 + 32 + j];
        } else {
            r = b_e2n[k];
        }
        BpB[ij*32 + k] = r;
    } else if (t < 73920) {
        // node mixing: [x;1] (33) x [attr;1] (4)
        int u = t - 69696;
        int k = u & 31, ij = u >> 5;   // ij in [0,132)
        int i = ij >> 2, j = ij & 3;
        float r;
        if (i < 32 && j < 3) {
            r = 0.f;
            #pragma unroll
            for (int m = 0; m < 32; ++m) r += W_mix_xn[k*67 + 35 + m] * B_mix_xn[m*96 + i*3 + j];
        } else if (i < 32 && j == 3) {
            r = W_mix_xn[k*67 + i];
        } else if (i == 32 && j < 3) {
            r = W_mix_xn[k*67 + 32 + j];
        } else {
            r = b_mix_xn[k];
        }
        BpN[ij*32 + k] = r;
    } else if (t < 74976) {
        int u = t - 73920;
        int k = u & 31, i = u >> 5;    // i in [0,33)
        WxE[i*32 + k] = (i < 32) ? W_mix_xe[k*65 + i] : b_mix_xe[k];
    } else if (t < 76032) {
        int u = t - 74976;
        int k = u & 31, i = u >> 5;
        float r;
        if (i < 32) {
            r = 0.f;
            #pragma unroll
            for (int m = 0; m < 32; ++m) r += W_mix_xe[k*65 + 33 + m] * B_mix_xe[m*32 + i];
        } else {
            r = W_mix_xe[k*65 + 32];   // attr column
        }
        CtE[i*32 + k] = r;
    }
}

__global__ void zero_kernel(float4* __restrict__ p, int n4) {
    int i = blockIdx.x * blockDim.x + threadIdx.x;
    int stride = gridDim.x * blockDim.x;
    float4 z = {0.f, 0.f, 0.f, 0.f};
    for (; i < n4; i += stride) p[i] = z;
}

__global__ __launch_bounds__(256) void node_kernel(
    const float* __restrict__ xn, const float* __restrict__ xn_attr,
    const float* __restrict__ BpN, float* __restrict__ xn_norm) {
    int n = blockIdx.x * 256 + threadIdx.x;
    if (n >= N_NODES) return;
    float x[33];
    const float4* xr = (const float4*)(xn + (size_t)n * 32);
    #pragma unroll
    for (int q = 0; q < 8; ++q) {
        float4 v = xr[q];
        x[q*4+0] = v.x; x[q*4+1] = v.y; x[q*4+2] = v.z; x[q*4+3] = v.w;
    }
    x[32] = 1.f;
    float at[4];
    at[0] = xn_attr[n*3]; at[1] = xn_attr[n*3+1]; at[2] = xn_attr[n*3+2]; at[3] = 1.f;

    float acc[32];
    #pragma unroll
    for (int k = 0; k < 32; ++k) acc[k] = 0.f;

    #pragma unroll
    for (int i = 0; i < 33; ++i) {
        #pragma unroll
        for (int j = 0; j < 4; ++j) {
            float s = x[i] * at[j];
            const float* bp = BpN + (i*4 + j) * 32;
            #pragma unroll
            for (int k = 0; k < 32; ++k) acc[k] = fmaf(bp[k], s, acc[k]);
        }
    }
    // row std (ddof = 1)
    float mean = 0.f;
    #pragma unroll
    for (int k = 0; k < 32; ++k) mean += acc[k];
    mean *= (1.0f / 32.0f);
    float var = 0.f;
    #pragma unroll
    for (int k = 0; k < 32; ++k) { float d = acc[k] - mean; var += d * d; }
    var *= (1.0f / 31.0f);
    float inv = 1.0f / (sqrtf(var) + EPS);
    float4* out = (float4*)(xn_norm + (size_t)n * 32);
    #pragma unroll
    for (int q = 0; q < 8; ++q) {
        float4 v;
        v.x = acc[q*4+0]*inv; v.y = acc[q*4+1]*inv; v.z = acc[q*4+2]*inv; v.w = acc[q*4+3]*inv;
        out[q] = v;
    }
}

__global__ __launch_bounds__(256) void edge_kernel(
    const float* __restrict__ xn_norm,
    const float* __restrict__ xe_attr,
    const int* __restrict__ xe_src, const int* __restrict__ xe_dst,
    const float* __restrict__ W_fc1, const float* __restrict__ b_fc1,
    const float* __restrict__ W_fc2, const float* __restrict__ b_fc2,
    const float* __restrict__ BpA,
    const float* __restrict__ WxE, const float* __restrict__ CtE,
    float* __restrict__ acc1, float* __restrict__ acc2) {
    __shared__ float sbl[256 * 33];   // per-thread b-vector (stride 33 -> conflict-free)
    int e = blockIdx.x * 256 + threadIdx.x;
    if (e >= N_EDGES) return;
    int src = xe_src[e], dst = xe_dst[e];
    float attr = xe_attr[e];

    float a[33];
    float* myb = &sbl[threadIdx.x * 33];
    const float4* gp = (const float4*)(xn_norm + (size_t)src * 32);
    const float4* dp = (const float4*)(xn_norm + (size_t)dst * 32);
    #pragma unroll
    for (int q = 0; q < 8; ++q) {
        float4 g = gp[q], d = dp[q];
        float gg[4] = {g.x, g.y, g.z, g.w};
        float dd[4] = {d.x, d.y, d.z, d.w};
        #pragma unroll
        for (int c = 0; c < 4; ++c) {
            int k = q*4 + c;
            float w = silu_f(attr * W_fc1[k] + b_fc1[k]);
            a[k] = w * (gg[c] - dd[c]);
            myb[k] = w * (gg[c] + dd[c]) * 0.5f;
        }
    }
    a[32] = 1.f;
    myb[32] = 1.f;

    // xe1 = [a;1]^T M [b;1]  (extended bilinear, W and bias folded)
    float acc[32];
    #pragma unroll
    for (int k = 0; k < 32; ++k) acc[k] = 0.f;
    #pragma unroll
    for (int i = 0; i < 33; ++i) {
        float ai = a[i];
        const float* bp = BpA + i * 33 * 32;
        #pragma unroll 2
        for (int j = 0; j < 33; ++j) {
            float s = ai * myb[j];
            const float* bpj = bp + j * 32;
            #pragma unroll
            for (int k = 0; k < 32; ++k) acc[k] = fmaf(bpj[k], s, acc[k]);
        }
    }

    // mix_xe folded: y = (Wx + attr*Ct) @ [xe1;1]
    float y[32];
    #pragma unroll
    for (int k = 0; k < 32; ++k) y[k] = 0.f;
    #pragma unroll
    for (int i = 0; i < 33; ++i) {
        float xi = (i < 32) ? acc[i] : 1.0f;
        const float* wx = WxE + i * 32;
        const float* ct = CtE + i * 32;
        #pragma unroll
        for (int k = 0; k < 32; ++k)
            y[k] = fmaf(fmaf(attr, ct[k], wx[k]), xi, y[k]);
    }

    // row std (ddof = 1)
    float mean = 0.f;
    #pragma unroll
    for (int k = 0; k < 32; ++k) mean += y[k];
    mean *= (1.0f / 32.0f);
    float var = 0.f;
    #pragma unroll
    for (int k = 0; k < 32; ++k) { float d = y[k] - mean; var += d * d; }
    var *= (1.0f / 31.0f);
    float inv = 1.0f / (sqrtf(var) + EPS);

    // w2 * xe, scatter
    float* p1 = acc1 + (size_t)dst * 32;
    float* p2 = acc2 + (size_t)src * 32;
    #pragma unroll
    for (int k = 0; k < 32; ++k) {
        float w2 = silu_f(attr * W_fc2[k] + b_fc2[k]);
        float v = w2 * y[k] * inv;
        unsafeAtomicAdd(p1 + k, v);
        unsafeAtomicAdd(p2 + k, v);
    }
}

__global__ __launch_bounds__(256) void final_kernel(
    const float* __restrict__ acc1, const float* __restrict__ acc2,
    const float* __restrict__ BpB, float* __restrict__ out) {
    __shared__ float sbl[256 * 33];
    int n = blockIdx.x * 256 + threadIdx.x;
    if (n >= N_NODES) return;
    float dv[33];
    float* myb = &sbl[threadIdx.x * 33];
    const float4* p1 = (const float4*)(acc1 + (size_t)n * 32);
    const float4* p2 = (const float4*)(acc2 + (size_t)n * 32);
    #pragma unroll
    for (int q = 0; q < 8; ++q) {
        float4 u1 = p1[q], u2 = p2[q];
        float a1[4] = {u1.x, u1.y, u1.z, u1.w};
        float a2[4] = {u2.x, u2.y, u2.z, u2.w};
        #pragma unroll
        for (int c = 0; c < 4; ++c) {
            int k = q*4 + c;
            dv[k]  = (a1[c] - a2[c]) * NORMC;
            myb[k] = (a1[c] + a2[c]) * NORMC;
        }
    }
    dv[32] = 1.f;
    myb[32] = 1.f;

    float acc[32];
    #pragma unroll
    for (int k = 0; k < 32; ++k) acc[k] = 0.f;
    #pragma unroll
    for (int i = 0; i < 33; ++i) {
        float ai = dv[i];
        const float* bp = BpB + i * 33 * 32;
        #pragma unroll 2
        for (int j = 0; j < 33; ++j) {
            float s = ai * myb[j];
            const float* bpj = bp + j * 32;
            #pragma unroll
            for (int k = 0; k < 32; ++k) acc[k] = fmaf(bpj[k], s, acc[k]);
        }
    }
    // silu, then row std (ddof = 1)
    float z[32];
    float mean = 0.f;
    #pragma unroll
    for (int k = 0; k < 32; ++k) { z[k] = silu_f(acc[k]); mean += z[k]; }
    mean *= (1.0f / 32.0f);
    float var = 0.f;
    #pragma unroll
    for (int k = 0; k < 32; ++k) { float d = z[k] - mean; var += d * d; }
    var *= (1.0f / 31.0f);
    float inv = 1.0f / (sqrtf(var) + EPS);
    float4* op = (float4*)(out + (size_t)n * 32);
    #pragma unroll
    for (int q = 0; q < 8; ++q) {
        float4 v;
        v.x = z[q*4+0]*inv; v.y = z[q*4+1]*inv; v.z = z[q*4+2]*inv; v.w = z[q*4+3]*inv;
        op[q] = v;
    }
}

extern "C" void kernel_launch(void* const* d_in, const int* in_sizes, int n_in,
                              void* d_out, int out_size, void* d_ws, size_t ws_size,
                              hipStream_t stream) {
    const float* xn       = (const float*)d_in[0];
    const float* xn_attr  = (const float*)d_in[1];
    const float* xe_attr  = (const float*)d_in[2];
    const int*   xe_src   = (const int*)d_in[3];
    const int*   xe_dst   = (const int*)d_in[4];
    const float* W_fc1    = (const float*)d_in[5];
    const float* b_fc1    = (const float*)d_in[6];
    const float* W_fc2    = (const float*)d_in[7];
    const float* b_fc2    = (const float*)d_in[8];
    const float* B_mix_xn = (const float*)d_in[9];
    const float* W_mix_xn = (const float*)d_in[10];
    const float* b_mix_xn = (const float*)d_in[11];
    const float* B_n2e    = (const float*)d_in[12];
    const float* W_n2e    = (const float*)d_in[13];
    const float* b_n2e    = (const float*)d_in[14];
    const float* B_mix_xe = (const float*)d_in[15];
    const float* W_mix_xe = (const float*)d_in[16];
    const float* b_mix_xe = (const float*)d_in[17];
    const float* B_e2n    = (const float*)d_in[18];
    const float* W_e2n    = (const float*)d_in[19];
    const float* b_e2n    = (const float*)d_in[20];

    float* ws      = (float*)d_ws;
    float* xn_norm = ws;
    float* acc1    = ws + 3200000;
    float* acc2    = ws + 6400000;
    float* BpA     = ws + 9600000;
    float* BpB     = BpA + 34848;
    float* BpN     = BpB + 34848;
    float* WxE     = BpN + 4224;
    float* CtE     = WxE + 1056;

    prep_kernel<<<297, 256, 0, stream>>>(W_n2e, B_n2e, b_n2e,
                                         W_e2n, B_e2n, b_e2n,
                                         W_mix_xn, B_mix_xn, b_mix_xn,
                                         W_mix_xe, B_mix_xe, b_mix_xe,
                                         BpA, BpB, BpN, WxE, CtE);
    zero_kernel<<<2048, 256, 0, stream>>>((float4*)acc1, 1600000);
    node_kernel<<<391, 256, 0, stream>>>(xn, xn_attr, BpN, xn_norm);
    edge_kernel<<<7813, 256, 0, stream>>>(xn_norm, xe_attr, xe_src, xe_dst,
                                          W_fc1, b_fc1, W_fc2, b_fc2,
                                          BpA, WxE, CtE, acc1, acc2);
    final_kernel<<<391, 256, 0, stream>>>(acc1, acc2, BpB, (float*)d_out);
}

// Round 2
// 6510.188 us; speedup vs baseline: 1.1297x; 1.1297x over previous
//
#include <hip/hip_runtime.h>
#include <hip/hip_bf16.h>

#define N_NODES 100000
#define N_EDGES 2000000
#define EPS 1e-9f
#define NORMC 0.22360679774997896f  // 1/sqrt(20)

typedef short s8 __attribute__((ext_vector_type(8)));
typedef float f4 __attribute__((ext_vector_type(4)));

__device__ __forceinline__ float silu_f(float x) {
    return x / (1.0f + __expf(-x));
}

__device__ __forceinline__ ushort f2bfu(float f) {
    union { __hip_bfloat16 b; ushort u; } cv;
    cv.b = __float2bfloat16(f);
    return cv.u;
}

__device__ __forceinline__ uint pkbf(float lo, float hi) {
    float2 t; t.x = lo; t.y = hi;
    union { __hip_bfloat162 b; uint u; } cv;
    cv.b = __float22bfloat162_rn(t);
    return cv.u;
}

// ---------------------------------------------------------------------------
// Workspace (floats):
//   xn_norm : 3,200,000
//   acc1    : 3,200,000
//   acc2    : 3,200,000
//   MF      : 17,408 f32-slots (34816 bf16)  edge bilinear fragments
//   MG      : 17,408 f32-slots               e2n bilinear fragments
//   BpN     : 4,224
//   WxE     : 1,056
//   CtE     : 1,056
// MF/MG layout (ushort): [((kk*2+nt)*64 + lane)*8 + t], kk in [0,34):
//   kk<33 : value Mext[n][i=kk][j=kl];  kk==33 : Mext[n][i=kl][32]
//   n = nt*16 + (lane&15), kl = ((lane>>4)&3)*8 + t
// Mext[k][i][j]: i<32,j<32 -> sum_m W[k,64+m] B[m,i,j];
//   j==32 -> W[k,i]; i==32 -> W[k,32+j]; both -> bias[k]
// ---------------------------------------------------------------------------

__device__ float mext(const float* __restrict__ W, const float* __restrict__ B,
                      const float* __restrict__ bias, int n, int i, int j) {
    if (i < 32 && j < 32) {
        float r = 0.f;
        #pragma unroll
        for (int m = 0; m < 32; ++m) r += W[n*96 + 64 + m] * B[m*1024 + i*32 + j];
        return r;
    }
    if (i < 32) return W[n*96 + i];        // j == 32
    if (j < 32) return W[n*96 + 32 + j];   // i == 32
    return bias[n];
}

__global__ void prep_kernel(const float* __restrict__ W_n2e, const float* __restrict__ B_n2e,
                            const float* __restrict__ b_n2e,
                            const float* __restrict__ W_e2n, const float* __restrict__ B_e2n,
                            const float* __restrict__ b_e2n,
                            const float* __restrict__ W_mix_xn, const float* __restrict__ B_mix_xn,
                            const float* __restrict__ b_mix_xn,
                            const float* __restrict__ W_mix_xe, const float* __restrict__ B_mix_xe,
                            const float* __restrict__ b_mix_xe,
                            ushort* __restrict__ MF, ushort* __restrict__ MG,
                            float* __restrict__ BpN, float* __restrict__ WxE,
                            float* __restrict__ CtE) {
    int t = blockIdx.x * blockDim.x + threadIdx.x;
    if (t < 69632) {
        int u = (t < 34816) ? t : t - 34816;
        int tt = u & 7, lane = (u >> 3) & 63, rest = u >> 9;
        int nt = rest & 1, kk = rest >> 1;
        int n = nt*16 + (lane & 15);
        int kl = ((lane >> 4) & 3) * 8 + tt;
        int i, j;
        if (kk < 33) { i = kk; j = kl; } else { i = kl; j = 32; }
        if (t < 34816) MF[u] = f2bfu(mext(W_n2e, B_n2e, b_n2e, n, i, j));
        else           MG[u] = f2bfu(mext(W_e2n, B_e2n, b_e2n, n, i, j));
    } else if (t < 73856) {
        int u = t - 69632;
        int k = u & 31, ij = u >> 5;   // ij in [0,132)
        int i = ij >> 2, j = ij & 3;
        float r;
        if (i < 32 && j < 3) {
            r = 0.f;
            #pragma unroll
            for (int m = 0; m < 32; ++m) r += W_mix_xn[k*67 + 35 + m] * B_mix_xn[m*96 + i*3 + j];
        } else if (i < 32 && j == 3) {
            r = W_mix_xn[k*67 + i];
        } else if (i == 32 && j < 3) {
            r = W_mix_xn[k*67 + 32 + j];
        } else {
            r = b_mix_xn[k];
        }
        BpN[ij*32 + k] = r;
    } else if (t < 74912) {
        int u = t - 73856;
        int k = u & 31, i = u >> 5;    // i in [0,33)
        WxE[i*32 + k] = (i < 32) ? W_mix_xe[k*65 + i] : b_mix_xe[k];
    } else if (t < 75968) {
        int u = t - 74912;
        int k = u & 31, i = u >> 5;
        float r;
        if (i < 32) {
            r = 0.f;
            #pragma unroll
            for (int m = 0; m < 32; ++m) r += W_mix_xe[k*65 + 33 + m] * B_mix_xe[m*32 + i];
        } else {
            r = W_mix_xe[k*65 + 32];
        }
        CtE[i*32 + k] = r;
    }
}

__global__ void zero_kernel(float4* __restrict__ p, int n4) {
    int i = blockIdx.x * blockDim.x + threadIdx.x;
    int stride = gridDim.x * blockDim.x;
    float4 z = {0.f, 0.f, 0.f, 0.f};
    for (; i < n4; i += stride) p[i] = z;
}

__global__ __launch_bounds__(256) void node_kernel(
    const float* __restrict__ xn, const float* __restrict__ xn_attr,
    const float* __restrict__ BpN, float* __restrict__ xn_norm) {
    int n = blockIdx.x * 256 + threadIdx.x;
    if (n >= N_NODES) return;
    float x[33];
    const float4* xr = (const float4*)(xn + (size_t)n * 32);
    #pragma unroll
    for (int q = 0; q < 8; ++q) {
        float4 v = xr[q];
        x[q*4+0] = v.x; x[q*4+1] = v.y; x[q*4+2] = v.z; x[q*4+3] = v.w;
    }
    x[32] = 1.f;
    float at[4];
    at[0] = xn_attr[n*3]; at[1] = xn_attr[n*3+1]; at[2] = xn_attr[n*3+2]; at[3] = 1.f;

    float acc[32];
    #pragma unroll
    for (int k = 0; k < 32; ++k) acc[k] = 0.f;
    #pragma unroll
    for (int i = 0; i < 33; ++i) {
        #pragma unroll
        for (int j = 0; j < 4; ++j) {
            float s = x[i] * at[j];
            const float* bp = BpN + (i*4 + j) * 32;
            #pragma unroll
            for (int k = 0; k < 32; ++k) acc[k] = fmaf(bp[k], s, acc[k]);
        }
    }
    float mean = 0.f;
    #pragma unroll
    for (int k = 0; k < 32; ++k) mean += acc[k];
    mean *= (1.0f / 32.0f);
    float var = 0.f;
    #pragma unroll
    for (int k = 0; k < 32; ++k) { float d = acc[k] - mean; var += d * d; }
    var *= (1.0f / 31.0f);
    float inv = 1.0f / (sqrtf(var) + EPS);
    float4* out = (float4*)(xn_norm + (size_t)n * 32);
    #pragma unroll
    for (int q = 0; q < 8; ++q) {
        float4 v;
        v.x = acc[q*4+0]*inv; v.y = acc[q*4+1]*inv; v.z = acc[q*4+2]*inv; v.w = acc[q*4+3]*inv;
        out[q] = v;
    }
}

// Shared GEMM phase: 256 rows staged in LDS -> per-wave 4 groups of 16 rows,
// 34 MFMA K-steps, result written back into a_f[row*33 + 0..31].
// a_f: [256][33] f32 (row r col kk = a_r[kk]; col 32 = 1)
// ab : [256][88] ushort: [0..31] = b bf16, [48..79] = a bf16
__device__ __forceinline__ void gemm_phase(float* __restrict__ a_f, const ushort* __restrict__ ab,
                                           const ushort* __restrict__ Mfrag,
                                           const float* __restrict__ biasv, int tid) {
    int lane = tid & 63, wv = tid >> 6;
    int m = lane & 15, h = lane >> 4;
    int base = wv * 64;
    float bfv[4][8];
    #pragma unroll
    for (int g = 0; g < 4; ++g) {
        union { s8 v; ushort s[8]; } braw;
        braw.v = *(const s8*)&ab[(size_t)(base + g*16 + m) * 88 + h*8];
        #pragma unroll
        for (int t = 0; t < 8; ++t) {
            union { uint u; float f; } cv; cv.u = ((uint)braw.s[t]) << 16;
            bfv[g][t] = cv.f;
        }
    }
    f4 c[4][2];
    #pragma unroll
    for (int g = 0; g < 4; ++g) {
        c[g][0] = (f4){0.f, 0.f, 0.f, 0.f};
        c[g][1] = (f4){0.f, 0.f, 0.f, 0.f};
    }
    const s8* M8 = (const s8*)Mfrag;
    #pragma unroll
    for (int kk = 0; kk < 33; ++kk) {
        s8 mf0 = M8[(kk*2 + 0)*64 + lane];
        s8 mf1 = M8[(kk*2 + 1)*64 + lane];
        #pragma unroll
        for (int g = 0; g < 4; ++g) {
            float as = a_f[(size_t)(base + g*16 + m) * 33 + kk];
            union { s8 v; uint u[4]; } af;
            #pragma unroll
            for (int t = 0; t < 4; ++t) af.u[t] = pkbf(as * bfv[g][2*t], as * bfv[g][2*t+1]);
            c[g][0] = __builtin_amdgcn_mfma_f32_16x16x32_bf16(af.v, mf0, c[g][0], 0, 0, 0);
            c[g][1] = __builtin_amdgcn_mfma_f32_16x16x32_bf16(af.v, mf1, c[g][1], 0, 0, 0);
        }
    }
    {   // K-step 33: A = a (bf16) directly, covers j==32 column
        s8 mf0 = M8[(33*2 + 0)*64 + lane];
        s8 mf1 = M8[(33*2 + 1)*64 + lane];
        #pragma unroll
        for (int g = 0; g < 4; ++g) {
            s8 araw = *(const s8*)&ab[(size_t)(base + g*16 + m) * 88 + 48 + h*8];
            c[g][0] = __builtin_amdgcn_mfma_f32_16x16x32_bf16(araw, mf0, c[g][0], 0, 0, 0);
            c[g][1] = __builtin_amdgcn_mfma_f32_16x16x32_bf16(araw, mf1, c[g][1], 0, 0, 0);
        }
    }
    float b0 = biasv[m], b1 = biasv[16 + m];
    #pragma unroll
    for (int g = 0; g < 4; ++g) {
        int rowb = base + g*16 + h*4;
        #pragma unroll
        for (int r = 0; r < 4; ++r) {
            a_f[(size_t)(rowb + r) * 33 + m]      = c[g][0][r] + b0;
            a_f[(size_t)(rowb + r) * 33 + 16 + m] = c[g][1][r] + b1;
        }
    }
}

__global__ __launch_bounds__(256) void edge_kernel(
    const float* __restrict__ xn_norm, const float* __restrict__ xe_attr,
    const int* __restrict__ xe_src, const int* __restrict__ xe_dst,
    const float* __restrict__ W_fc1, const float* __restrict__ b_fc1,
    const float* __restrict__ W_fc2, const float* __restrict__ b_fc2,
    const ushort* __restrict__ MF, const float* __restrict__ biasE,
    const float* __restrict__ WxE, const float* __restrict__ CtE,
    float* __restrict__ acc1, float* __restrict__ acc2) {
    __shared__ __align__(16) float  a_f[256 * 33];
    __shared__ __align__(16) ushort ab[256 * 88];
    int tid = threadIdx.x;
    int e = blockIdx.x * 256 + tid;
    bool valid = e < N_EDGES;
    float attr = 0.f; int src = 0, dst = 0;
    if (valid) { attr = xe_attr[e]; src = xe_src[e]; dst = xe_dst[e]; }
    float vs = valid ? 1.f : 0.f;
    const float4* gp = (const float4*)(xn_norm + (size_t)src * 32);
    const float4* dp = (const float4*)(xn_norm + (size_t)dst * 32);
    #pragma unroll
    for (int q = 0; q < 8; ++q) {
        float4 g = gp[q], d = dp[q];
        float gg[4] = {g.x, g.y, g.z, g.w};
        float dd[4] = {d.x, d.y, d.z, d.w};
        #pragma unroll
        for (int cix = 0; cix < 4; ++cix) {
            int k = q*4 + cix;
            float w = silu_f(attr * W_fc1[k] + b_fc1[k]) * vs;
            float av = w * (gg[cix] - dd[cix]);
            float bv = w * (gg[cix] + dd[cix]) * 0.5f;
            a_f[tid*33 + k] = av;
            ab[tid*88 + k]      = f2bfu(bv);
            ab[tid*88 + 48 + k] = f2bfu(av);
        }
    }
    a_f[tid*33 + 32] = 1.f;
    __syncthreads();

    gemm_phase(a_f, ab, MF, biasE, tid);
    __syncthreads();

    if (!valid) return;
    // mix_xe folded: y[k] = sum_i (WxE[i][k] + attr*CtE[i][k]) * xe1_i  (i=32 -> 1)
    float y[32];
    #pragma unroll
    for (int k = 0; k < 32; ++k) y[k] = 0.f;
    for (int i = 0; i < 33; ++i) {
        float xi = (i < 32) ? a_f[tid*33 + i] : 1.0f;
        const float* wx = WxE + i * 32;
        const float* ct = CtE + i * 32;
        #pragma unroll
        for (int k = 0; k < 32; ++k)
            y[k] = fmaf(fmaf(attr, ct[k], wx[k]), xi, y[k]);
    }
    float mean = 0.f;
    #pragma unroll
    for (int k = 0; k < 32; ++k) mean += y[k];
    mean *= (1.0f / 32.0f);
    float var = 0.f;
    #pragma unroll
    for (int k = 0; k < 32; ++k) { float d = y[k] - mean; var += d * d; }
    var *= (1.0f / 31.0f);
    float inv = 1.0f / (sqrtf(var) + EPS);

    float* p1 = acc1 + (size_t)dst * 32;
    float* p2 = acc2 + (size_t)src * 32;
    #pragma unroll
    for (int k = 0; k < 32; ++k) {
        float w2 = silu_f(attr * W_fc2[k] + b_fc2[k]);
        float v = w2 * y[k] * inv;
        unsafeAtomicAdd(p1 + k, v);
        unsafeAtomicAdd(p2 + k, v);
    }
}

__global__ __launch_bounds__(256) void final_kernel(
    const float* __restrict__ acc1, const float* __restrict__ acc2,
    const ushort* __restrict__ MG, const float* __restrict__ biasG,
    float* __restrict__ out) {
    __shared__ __align__(16) float  a_f[256 * 33];
    __shared__ __align__(16) ushort ab[256 * 88];
    int tid = threadIdx.x;
    int n = blockIdx.x * 256 + tid;
    bool valid = n < N_NODES;
    int nn = valid ? n : 0;
    float vs = valid ? 1.f : 0.f;
    const float4* p1 = (const float4*)(acc1 + (size_t)nn * 32);
    const float4* p2 = (const float4*)(acc2 + (size_t)nn * 32);
    #pragma unroll
    for (int q = 0; q < 8; ++q) {
        float4 u1 = p1[q], u2 = p2[q];
        float a1[4] = {u1.x, u1.y, u1.z, u1.w};
        float a2[4] = {u2.x, u2.y, u2.z, u2.w};
        #pragma unroll
        for (int cix = 0; cix < 4; ++cix) {
            int k = q*4 + cix;
            float dv = (a1[cix] - a2[cix]) * NORMC * vs;
            float sv = (a1[cix] + a2[cix]) * NORMC * vs;
            a_f[tid*33 + k] = dv;
            ab[tid*88 + k]      = f2bfu(sv);
            ab[tid*88 + 48 + k] = f2bfu(dv);
        }
    }
    a_f[tid*33 + 32] = 1.f;
    __syncthreads();

    gemm_phase(a_f, ab, MG, biasG, tid);
    __syncthreads();

    if (!valid) return;
    float z[32];
    float mean = 0.f;
    #pragma unroll
    for (int k = 0; k < 32; ++k) { z[k] = silu_f(a_f[tid*33 + k]); mean += z[k]; }
    mean *= (1.0f / 32.0f);
    float var = 0.f;
    #pragma unroll
    for (int k = 0; k < 32; ++k) { float d = z[k] - mean; var += d * d; }
    var *= (1.0f / 31.0f);
    float inv = 1.0f / (sqrtf(var) + EPS);
    float4* op = (float4*)(out + (size_t)n * 32);
    #pragma unroll
    for (int q = 0; q < 8; ++q) {
        float4 v;
        v.x = z[q*4+0]*inv; v.y = z[q*4+1]*inv; v.z = z[q*4+2]*inv; v.w = z[q*4+3]*inv;
        op[q] = v;
    }
}

extern "C" void kernel_launch(void* const* d_in, const int* in_sizes, int n_in,
                              void* d_out, int out_size, void* d_ws, size_t ws_size,
                              hipStream_t stream) {
    const float* xn       = (const float*)d_in[0];
    const float* xn_attr  = (const float*)d_in[1];
    const float* xe_attr  = (const float*)d_in[2];
    const int*   xe_src   = (const int*)d_in[3];
    const int*   xe_dst   = (const int*)d_in[4];
    const float* W_fc1    = (const float*)d_in[5];
    const float* b_fc1    = (const float*)d_in[6];
    const float* W_fc2    = (const float*)d_in[7];
    const float* b_fc2    = (const float*)d_in[8];
    const float* B_mix_xn = (const float*)d_in[9];
    const float* W_mix_xn = (const float*)d_in[10];
    const float* b_mix_xn = (const float*)d_in[11];
    const float* B_n2e    = (const float*)d_in[12];
    const float* W_n2e    = (const float*)d_in[13];
    const float* b_n2e    = (const float*)d_in[14];
    const float* B_mix_xe = (const float*)d_in[15];
    const float* W_mix_xe = (const float*)d_in[16];
    const float* b_mix_xe = (const float*)d_in[17];
    const float* B_e2n    = (const float*)d_in[18];
    const float* W_e2n    = (const float*)d_in[19];
    const float* b_e2n    = (const float*)d_in[20];

    float* ws      = (float*)d_ws;
    float* xn_norm = ws;
    float* acc1    = ws + 3200000;
    float* acc2    = ws + 6400000;
    ushort* MF     = (ushort*)(ws + 9600000);
    ushort* MG     = MF + 34816;
    float* BpN     = ws + 9600000 + 34816;          // 2*17408 f32 slots for MF+MG
    float* WxE     = BpN + 4224;
    float* CtE     = WxE + 1056;

    prep_kernel<<<297, 256, 0, stream>>>(W_n2e, B_n2e, b_n2e,
                                         W_e2n, B_e2n, b_e2n,
                                         W_mix_xn, B_mix_xn, b_mix_xn,
                                         W_mix_xe, B_mix_xe, b_mix_xe,
                                         MF, MG, BpN, WxE, CtE);
    zero_kernel<<<2048, 256, 0, stream>>>((float4*)acc1, 1600000);
    node_kernel<<<391, 256, 0, stream>>>(xn, xn_attr, BpN, xn_norm);
    edge_kernel<<<7813, 256, 0, stream>>>(xn_norm, xe_attr, xe_src, xe_dst,
                                          W_fc1, b_fc1, W_fc2, b_fc2,
                                          MF, b_n2e, WxE, CtE, acc1, acc2);
    final_kernel<<<391, 256, 0, stream>>>(acc1, acc2, MG, b_e2n, (float*)d_out);
}